// Round 1
// baseline (105.170 us; speedup 1.0000x reference)
//
#include <hip/hip_runtime.h>
#include <math.h>

#define NSTEPS 128
#define HID 64
#define RAYS_PER_BLOCK 8
#define SAMPLES_PER_THREAD 4

// Each ray: 32 threads x 4 samples = 128 samples.
// Block: 256 threads = 8 rays. Grid: R/8 blocks.
__global__ __launch_bounds__(256) void nerf_render_kernel(
    const float* __restrict__ rays_o,   // [R,3]
    const float* __restrict__ rays_d,   // [R,3]
    const float* __restrict__ W1,       // [3,64]
    const float* __restrict__ W2,       // [3,64]
    const float* __restrict__ b1,       // [64]
    const float* __restrict__ w_sigma,  // [64,1]
    const float* __restrict__ W_color,  // [64,3]
    float* __restrict__ out_image,      // [R,3]
    float* __restrict__ out_depth,      // [R]
    float* __restrict__ out_weights,    // [R,128]
    float* __restrict__ out_wsum,       // [R]
    int R)
{
    // Packed weights in LDS: per hidden unit j:
    // [0..2]=W1[:,j]  [3..5]=W2[:,j]  [6]=b1[j]  [7]=w_sigma[j]  [8..10]=W_color[j,:]  [11]=pad
    __shared__ float wl[HID][12];
    const int tid = threadIdx.x;
    if (tid < HID) {
        const int j = tid;
        wl[j][0]  = W1[0 * HID + j];
        wl[j][1]  = W1[1 * HID + j];
        wl[j][2]  = W1[2 * HID + j];
        wl[j][3]  = W2[0 * HID + j];
        wl[j][4]  = W2[1 * HID + j];
        wl[j][5]  = W2[2 * HID + j];
        wl[j][6]  = b1[j];
        wl[j][7]  = w_sigma[j];
        wl[j][8]  = W_color[j * 3 + 0];
        wl[j][9]  = W_color[j * 3 + 1];
        wl[j][10] = W_color[j * 3 + 2];
        wl[j][11] = 0.0f;
    }
    __syncthreads();

    const int r   = tid >> 5;        // ray within block (0..7)
    const int l   = tid & 31;        // lane within ray (0..31)
    const int ray = blockIdx.x * RAYS_PER_BLOCK + r;
    if (ray >= R) return;            // R % 8 == 0 in practice -> no divergence

    const float o0 = rays_o[ray * 3 + 0];
    const float o1 = rays_o[ray * 3 + 1];
    const float o2 = rays_o[ray * 3 + 2];
    const float d0 = rays_d[ray * 3 + 0];
    const float d1 = rays_d[ray * 3 + 1];
    const float d2 = rays_d[ray * 3 + 2];

    // ---- near/far: cube AABB [-1,1]^3 ----
    const float inv0 = 1.0f / (d0 + 1e-15f);
    const float inv1 = 1.0f / (d1 + 1e-15f);
    const float inv2 = 1.0f / (d2 + 1e-15f);
    const float t0a = (-1.0f - o0) * inv0, t0b = (1.0f - o0) * inv0;
    const float t1a = (-1.0f - o1) * inv1, t1b = (1.0f - o1) * inv1;
    const float t2a = (-1.0f - o2) * inv2, t2b = (1.0f - o2) * inv2;
    float near = fmaxf(fmaxf(fminf(t0a, t0b), fminf(t1a, t1b)), fminf(t2a, t2b));
    float far  = fminf(fminf(fmaxf(t0a, t0b), fmaxf(t1a, t1b)), fmaxf(t2a, t2b));
    if (far < near) { near = 1e9f; far = 1e9f; }
    near = fmaxf(near, 0.05f);
    const float span = far - near;
    const float sample_dist = span * (1.0f / (NSTEPS - 1));

    // ---- sample points ----
    float z[SAMPLES_PER_THREAD];
    float x0[SAMPLES_PER_THREAD], x1[SAMPLES_PER_THREAD], x2[SAMPLES_PER_THREAD];
#pragma unroll
    for (int k = 0; k < SAMPLES_PER_THREAD; k++) {
        const int s = l * SAMPLES_PER_THREAD + k;
        const float t = (float)s * (1.0f / (NSTEPS - 1));
        z[k] = near + span * t;
        x0[k] = fminf(fmaxf(fmaf(d0, z[k], o0), -1.0f), 1.0f);
        x1[k] = fminf(fmaxf(fmaf(d1, z[k], o1), -1.0f), 1.0f);
        x2[k] = fminf(fmaxf(fmaf(d2, z[k], o2), -1.0f), 1.0f);
    }

    // ---- MLP: accumulate sigma-dot and color-dots over 64 hidden units ----
    float aS[SAMPLES_PER_THREAD] = {0.f, 0.f, 0.f, 0.f};
    float aR[SAMPLES_PER_THREAD] = {0.f, 0.f, 0.f, 0.f};
    float aG[SAMPLES_PER_THREAD] = {0.f, 0.f, 0.f, 0.f};
    float aB[SAMPLES_PER_THREAD] = {0.f, 0.f, 0.f, 0.f};

#pragma unroll 8
    for (int j = 0; j < HID; j++) {
        const float4 A  = *(const float4*)&wl[j][0];   // W1[0..2][j], W2[0][j]
        const float4 Bq = *(const float4*)&wl[j][4];   // W2[1..2][j], b1[j], ws[j]
        const float4 Cq = *(const float4*)&wl[j][8];   // Wc[j][0..2], pad
        const float base = fmaf(d0, A.w, fmaf(d1, Bq.x, fmaf(d2, Bq.y, Bq.z)));
#pragma unroll
        for (int k = 0; k < SAMPLES_PER_THREAD; k++) {
            float h = fmaf(x0[k], A.x, fmaf(x1[k], A.y, fmaf(x2[k], A.z, base)));
            h = fmaxf(h, 0.0f);                         // relu
            aS[k] = fmaf(h, Bq.w, aS[k]);
            aR[k] = fmaf(h, Cq.x, aR[k]);
            aG[k] = fmaf(h, Cq.y, aG[k]);
            aB[k] = fmaf(h, Cq.z, aB[k]);
        }
    }

    // ---- sigma -> alpha, thread-local transmittance ----
    float alpha[SAMPLES_PER_THREAD], Tloc[SAMPLES_PER_THREAD];
    float pl = 1.0f;  // running product of (1 - alpha + 1e-15) over this thread's samples
#pragma unroll
    for (int k = 0; k < SAMPLES_PER_THREAD; k++) {
        const float x = aS[k];
        // softplus via logaddexp(x, 0): numerically stable
        const float sig = fmaxf(x, 0.0f) + log1pf(expf(-fabsf(x)));
        alpha[k] = 1.0f - expf(-sample_dist * sig);
        Tloc[k] = pl;
        pl *= (1.0f - alpha[k] + 1e-15f);
    }

    // ---- exclusive scan of products across the 32 lanes of this ray ----
    float inc = pl;
#pragma unroll
    for (int dlt = 1; dlt < 32; dlt <<= 1) {
        const float v = __shfl_up(inc, dlt, 32);
        if (l >= dlt) inc *= v;
    }
    float excl = __shfl_up(inc, 1, 32);
    if (l == 0) excl = 1.0f;

    // ---- weights, color, depth ----
    float w[SAMPLES_PER_THREAD];
    float wsum = 0.f, dep = 0.f, im0 = 0.f, im1 = 0.f, im2 = 0.f;
#pragma unroll
    for (int k = 0; k < SAMPLES_PER_THREAD; k++) {
        const float T  = excl * Tloc[k];
        const float wt = alpha[k] * T;
        w[k] = wt;
        wsum += wt;
        dep  += wt * z[k];
        const float cr = 1.0f / (1.0f + expf(-aR[k]));
        const float cg = 1.0f / (1.0f + expf(-aG[k]));
        const float cb = 1.0f / (1.0f + expf(-aB[k]));
        im0 += wt * cr;
        im1 += wt * cg;
        im2 += wt * cb;
    }

    // weights out: coalesced float4 per thread
    *(float4*)&out_weights[(size_t)ray * NSTEPS + l * SAMPLES_PER_THREAD] =
        make_float4(w[0], w[1], w[2], w[3]);

    // ---- reduce across the ray's 32 lanes ----
#pragma unroll
    for (int dlt = 16; dlt >= 1; dlt >>= 1) {
        wsum += __shfl_down(wsum, dlt, 32);
        dep  += __shfl_down(dep,  dlt, 32);
        im0  += __shfl_down(im0,  dlt, 32);
        im1  += __shfl_down(im1,  dlt, 32);
        im2  += __shfl_down(im2,  dlt, 32);
    }
    if (l == 0) {
        out_image[ray * 3 + 0] = im0;
        out_image[ray * 3 + 1] = im1;
        out_image[ray * 3 + 2] = im2;
        out_depth[ray] = dep;
        out_wsum[ray]  = wsum;
    }
}

extern "C" void kernel_launch(void* const* d_in, const int* in_sizes, int n_in,
                              void* d_out, int out_size, void* d_ws, size_t ws_size,
                              hipStream_t stream) {
    const float* rays_o  = (const float*)d_in[0];
    const float* rays_d  = (const float*)d_in[1];
    const float* W1      = (const float*)d_in[2];
    const float* W2      = (const float*)d_in[3];
    const float* b1      = (const float*)d_in[4];
    const float* w_sigma = (const float*)d_in[5];
    const float* W_color = (const float*)d_in[6];

    const int R = in_sizes[0] / 3;  // B*N rays

    float* out         = (float*)d_out;
    float* out_image   = out;                               // [R,3]
    float* out_depth   = out_image + (size_t)R * 3;         // [R]
    float* out_weights = out_depth + R;                     // [R,128]
    float* out_wsum    = out_weights + (size_t)R * NSTEPS;  // [R]

    const int blocks = (R + RAYS_PER_BLOCK - 1) / RAYS_PER_BLOCK;
    nerf_render_kernel<<<blocks, 256, 0, stream>>>(
        rays_o, rays_d, W1, W2, b1, w_sigma, W_color,
        out_image, out_depth, out_weights, out_wsum, R);
}

// Round 2
// 97.401 us; speedup vs baseline: 1.0798x; 1.0798x over previous
//
#include <hip/hip_runtime.h>
#include <math.h>

#define NSTEPS 128
#define HID 64
#define RAYS_PER_BLOCK 8
#define SAMPLES_PER_THREAD 4

// Each ray: 32 threads x 4 samples = 128 samples.
// Block: 256 threads = 8 rays. Grid: R/8 blocks.
// Weights are wave-uniform -> loaded via scalar pipe (s_load) into SGPRs,
// keeping the LDS pipe idle and VGPR pressure low.
__global__ __launch_bounds__(256, 6) void nerf_render_kernel(
    const float* __restrict__ rays_o,   // [R,3]
    const float* __restrict__ rays_d,   // [R,3]
    const float* __restrict__ W1,       // [3,64]
    const float* __restrict__ W2,       // [3,64]
    const float* __restrict__ b1,       // [64]
    const float* __restrict__ w_sigma,  // [64]
    const float* __restrict__ W_color,  // [64,3]
    float* __restrict__ out_image,      // [R,3]
    float* __restrict__ out_depth,      // [R]
    float* __restrict__ out_weights,    // [R,128]
    float* __restrict__ out_wsum,       // [R]
    int R)
{
    const int tid = threadIdx.x;
    const int r   = tid >> 5;        // ray within block (0..7)
    const int l   = tid & 31;        // lane within ray (0..31)
    int ray = blockIdx.x * RAYS_PER_BLOCK + r;
    const bool valid = (ray < R);
    if (!valid) ray = R - 1;         // clamp; stores guarded below (R%8==0 -> never hit)

    const float o0 = rays_o[ray * 3 + 0];
    const float o1 = rays_o[ray * 3 + 1];
    const float o2 = rays_o[ray * 3 + 2];
    const float d0 = rays_d[ray * 3 + 0];
    const float d1 = rays_d[ray * 3 + 1];
    const float d2 = rays_d[ray * 3 + 2];

    // ---- near/far: cube AABB [-1,1]^3 ----
    const float inv0 = 1.0f / (d0 + 1e-15f);
    const float inv1 = 1.0f / (d1 + 1e-15f);
    const float inv2 = 1.0f / (d2 + 1e-15f);
    const float t0a = (-1.0f - o0) * inv0, t0b = (1.0f - o0) * inv0;
    const float t1a = (-1.0f - o1) * inv1, t1b = (1.0f - o1) * inv1;
    const float t2a = (-1.0f - o2) * inv2, t2b = (1.0f - o2) * inv2;
    float near = fmaxf(fmaxf(fminf(t0a, t0b), fminf(t1a, t1b)), fminf(t2a, t2b));
    float far  = fminf(fminf(fmaxf(t0a, t0b), fmaxf(t1a, t1b)), fmaxf(t2a, t2b));
    if (far < near) { near = 1e9f; far = 1e9f; }
    near = fmaxf(near, 0.05f);
    const float span = far - near;
    const float sample_dist = span * (1.0f / (NSTEPS - 1));

    // ---- sample points (z recomputed later; keep xyz only) ----
    float x0[SAMPLES_PER_THREAD], x1[SAMPLES_PER_THREAD], x2[SAMPLES_PER_THREAD];
#pragma unroll
    for (int k = 0; k < SAMPLES_PER_THREAD; k++) {
        const int s = l * SAMPLES_PER_THREAD + k;
        const float t = (float)s * (1.0f / (NSTEPS - 1));
        const float z = fmaf(span, t, near);
        x0[k] = fminf(fmaxf(fmaf(d0, z, o0), -1.0f), 1.0f);
        x1[k] = fminf(fmaxf(fmaf(d1, z, o1), -1.0f), 1.0f);
        x2[k] = fminf(fmaxf(fmaf(d2, z, o2), -1.0f), 1.0f);
    }

    // ---- MLP: accumulate sigma-dot and color-dots over 64 hidden units ----
    float aS[SAMPLES_PER_THREAD] = {0.f, 0.f, 0.f, 0.f};
    float aR[SAMPLES_PER_THREAD] = {0.f, 0.f, 0.f, 0.f};
    float aG[SAMPLES_PER_THREAD] = {0.f, 0.f, 0.f, 0.f};
    float aB[SAMPLES_PER_THREAD] = {0.f, 0.f, 0.f, 0.f};

    // Process hidden units in chunks of 4. All weight loads below have
    // wave-uniform addresses -> compiler scalarizes to s_load_dwordx4.
    for (int jc = 0; jc < HID; jc += 4) {
        const float4 w1x = *(const float4*)&W1[0 * HID + jc];  // W1[0][jc..jc+3]
        const float4 w1y = *(const float4*)&W1[1 * HID + jc];
        const float4 w1z = *(const float4*)&W1[2 * HID + jc];
        const float4 w2x = *(const float4*)&W2[0 * HID + jc];
        const float4 w2y = *(const float4*)&W2[1 * HID + jc];
        const float4 w2z = *(const float4*)&W2[2 * HID + jc];
        const float4 bb  = *(const float4*)&b1[jc];
        const float4 ws  = *(const float4*)&w_sigma[jc];
        const float4 wc0 = *(const float4*)&W_color[jc * 3 + 0];  // 12 contiguous floats
        const float4 wc1 = *(const float4*)&W_color[jc * 3 + 4];
        const float4 wc2 = *(const float4*)&W_color[jc * 3 + 8];

        const float c1x[4] = {w1x.x, w1x.y, w1x.z, w1x.w};
        const float c1y[4] = {w1y.x, w1y.y, w1y.z, w1y.w};
        const float c1z[4] = {w1z.x, w1z.y, w1z.z, w1z.w};
        const float c2x[4] = {w2x.x, w2x.y, w2x.z, w2x.w};
        const float c2y[4] = {w2y.x, w2y.y, w2y.z, w2y.w};
        const float c2z[4] = {w2z.x, w2z.y, w2z.z, w2z.w};
        const float cb[4]  = {bb.x, bb.y, bb.z, bb.w};
        const float cs[4]  = {ws.x, ws.y, ws.z, ws.w};
        const float ccr[4] = {wc0.x, wc0.w, wc1.z, wc2.y};  // W_color[j][0]
        const float ccg[4] = {wc0.y, wc1.x, wc1.w, wc2.z};  // W_color[j][1]
        const float ccb[4] = {wc0.z, wc1.y, wc2.x, wc2.w};  // W_color[j][2]

#pragma unroll
        for (int u = 0; u < 4; u++) {
            const float base = fmaf(d0, c2x[u], fmaf(d1, c2y[u], fmaf(d2, c2z[u], cb[u])));
#pragma unroll
            for (int k = 0; k < SAMPLES_PER_THREAD; k++) {
                float h = fmaf(x0[k], c1x[u], fmaf(x1[k], c1y[u], fmaf(x2[k], c1z[u], base)));
                h = fmaxf(h, 0.0f);                         // relu
                aS[k] = fmaf(h, cs[u],  aS[k]);
                aR[k] = fmaf(h, ccr[u], aR[k]);
                aG[k] = fmaf(h, ccg[u], aG[k]);
                aB[k] = fmaf(h, ccb[u], aB[k]);
            }
        }
    }

    // ---- sigma -> alpha, thread-local transmittance ----
    float alpha[SAMPLES_PER_THREAD], Tloc[SAMPLES_PER_THREAD];
    float pl = 1.0f;  // running product of (1 - alpha + 1e-15) over this thread's samples
#pragma unroll
    for (int k = 0; k < SAMPLES_PER_THREAD; k++) {
        const float x = aS[k];
        // softplus via max(x,0) + log(1+exp(-|x|)); fast intrinsics are
        // ~1e-6 abs accurate here, far under the 4.5e-2 threshold.
        const float sig = fmaxf(x, 0.0f) + __logf(1.0f + __expf(-fabsf(x)));
        alpha[k] = 1.0f - __expf(-sample_dist * sig);
        Tloc[k] = pl;
        pl *= (1.0f - alpha[k] + 1e-15f);
    }

    // ---- exclusive scan of products across the 32 lanes of this ray ----
    float inc = pl;
#pragma unroll
    for (int dlt = 1; dlt < 32; dlt <<= 1) {
        const float v = __shfl_up(inc, dlt, 32);
        if (l >= dlt) inc *= v;
    }
    float excl = __shfl_up(inc, 1, 32);
    if (l == 0) excl = 1.0f;

    // ---- weights, color, depth ----
    float w[SAMPLES_PER_THREAD];
    float wsum = 0.f, dep = 0.f, im0 = 0.f, im1 = 0.f, im2 = 0.f;
#pragma unroll
    for (int k = 0; k < SAMPLES_PER_THREAD; k++) {
        const int s = l * SAMPLES_PER_THREAD + k;
        const float t = (float)s * (1.0f / (NSTEPS - 1));
        const float z = fmaf(span, t, near);
        const float T  = excl * Tloc[k];
        const float wt = alpha[k] * T;
        w[k] = wt;
        wsum += wt;
        dep  += wt * z;
        const float cr = 1.0f / (1.0f + __expf(-aR[k]));
        const float cg = 1.0f / (1.0f + __expf(-aG[k]));
        const float cb2 = 1.0f / (1.0f + __expf(-aB[k]));
        im0 += wt * cr;
        im1 += wt * cg;
        im2 += wt * cb2;
    }

    if (valid) {
        // weights out: coalesced float4 per thread
        *(float4*)&out_weights[(size_t)ray * NSTEPS + l * SAMPLES_PER_THREAD] =
            make_float4(w[0], w[1], w[2], w[3]);
    }

    // ---- reduce across the ray's 32 lanes ----
#pragma unroll
    for (int dlt = 16; dlt >= 1; dlt >>= 1) {
        wsum += __shfl_down(wsum, dlt, 32);
        dep  += __shfl_down(dep,  dlt, 32);
        im0  += __shfl_down(im0,  dlt, 32);
        im1  += __shfl_down(im1,  dlt, 32);
        im2  += __shfl_down(im2,  dlt, 32);
    }
    if (l == 0 && valid) {
        out_image[ray * 3 + 0] = im0;
        out_image[ray * 3 + 1] = im1;
        out_image[ray * 3 + 2] = im2;
        out_depth[ray] = dep;
        out_wsum[ray]  = wsum;
    }
}

extern "C" void kernel_launch(void* const* d_in, const int* in_sizes, int n_in,
                              void* d_out, int out_size, void* d_ws, size_t ws_size,
                              hipStream_t stream) {
    const float* rays_o  = (const float*)d_in[0];
    const float* rays_d  = (const float*)d_in[1];
    const float* W1      = (const float*)d_in[2];
    const float* W2      = (const float*)d_in[3];
    const float* b1      = (const float*)d_in[4];
    const float* w_sigma = (const float*)d_in[5];
    const float* W_color = (const float*)d_in[6];

    const int R = in_sizes[0] / 3;  // B*N rays

    float* out         = (float*)d_out;
    float* out_image   = out;                               // [R,3]
    float* out_depth   = out_image + (size_t)R * 3;         // [R]
    float* out_weights = out_depth + R;                     // [R,128]
    float* out_wsum    = out_weights + (size_t)R * NSTEPS;  // [R]

    const int blocks = (R + RAYS_PER_BLOCK - 1) / RAYS_PER_BLOCK;
    nerf_render_kernel<<<blocks, 256, 0, stream>>>(
        rays_o, rays_d, W1, W2, b1, w_sigma, W_color,
        out_image, out_depth, out_weights, out_wsum, R);
}

// Round 5
// 90.367 us; speedup vs baseline: 1.1638x; 1.0778x over previous
//
#include <hip/hip_runtime.h>
#include <math.h>

#define NSTEPS 128
#define HID 64
#define RAYS_PER_BLOCK 16
#define THREADS_PER_RAY 16
#define SPT 8   // samples per thread

typedef _Float16 hf2 __attribute__((ext_vector_type(2)));

static __device__ __forceinline__ hf2 pk(float a, float b) {
    // __builtin_amdgcn_cvt_pkrtz returns __fp16x2 on this toolchain; same bits.
    auto v = __builtin_amdgcn_cvt_pkrtz(a, b);   // v_cvt_pkrtz_f16_f32
    return __builtin_bit_cast(hf2, v);
}
static __device__ __forceinline__ unsigned bits(hf2 v) {
    return __builtin_bit_cast(unsigned, v);
}
static __device__ __forceinline__ hf2 unbits(unsigned u) {
    return __builtin_bit_cast(hf2, u);
}

static __device__ __forceinline__ float dot2acc(hf2 h, hf2 w, float acc) {
#if __has_builtin(__builtin_amdgcn_fdot2)
    return __builtin_amdgcn_fdot2(h, w, acc, false);   // v_dot2_f32_f16
#else
    acc = fmaf((float)h[0], (float)w[0], acc);
    acc = fmaf((float)h[1], (float)w[1], acc);
    return acc;
#endif
}

// Block: 256 threads = 16 rays x 16 threads. Each thread: 8 consecutive samples.
// Weights pre-packed to f16 pairs in LDS once per block; per-ray base
// (b1 + d@W2) folded into the layer-1 bias pair. Packed f16 VALU
// (v_pk_fma_f16 / v_pk_max_f16 / v_dot2_f32_f16) halves the MLP inst count.
__global__ __launch_bounds__(256, 4) void nerf_render_kernel(
    const float* __restrict__ rays_o,   // [R,3]
    const float* __restrict__ rays_d,   // [R,3]
    const float* __restrict__ W1,       // [3,64]
    const float* __restrict__ W2,       // [3,64]
    const float* __restrict__ b1,       // [64]
    const float* __restrict__ w_sigma,  // [64]
    const float* __restrict__ W_color,  // [64,3]
    float* __restrict__ out_image,      // [R,3]
    float* __restrict__ out_depth,      // [R]
    float* __restrict__ out_weights,    // [R,128]
    float* __restrict__ out_wsum,       // [R]
    int R)
{
    // A[r][jp]: {w1x2, w1y2, w1z2, base2} per ray r, hidden-pair jp.
    // Row stride 33 (pad) so rays in a wave don't alias banks.
    __shared__ uint4 ldsA[RAYS_PER_BLOCK][33];
    __shared__ uint4 ldsB[32];           // {ws2, wcr2, wcg2, wcb2} per jp

    const int tid = threadIdx.x;

    // ---- cooperative LDS build: 512 A-entries over 256 threads ----
    for (int e = tid; e < RAYS_PER_BLOCK * 32; e += 256) {
        const int r  = e >> 5;
        const int jp = e & 31;
        const int j0 = jp * 2;
        int gray = blockIdx.x * RAYS_PER_BLOCK + r;
        if (gray >= R) gray = R - 1;
        const float dd0 = rays_d[gray * 3 + 0];
        const float dd1 = rays_d[gray * 3 + 1];
        const float dd2 = rays_d[gray * 3 + 2];
        const float2 w1x = *(const float2*)&W1[0 * HID + j0];
        const float2 w1y = *(const float2*)&W1[1 * HID + j0];
        const float2 w1z = *(const float2*)&W1[2 * HID + j0];
        const float2 w2x = *(const float2*)&W2[0 * HID + j0];
        const float2 w2y = *(const float2*)&W2[1 * HID + j0];
        const float2 w2z = *(const float2*)&W2[2 * HID + j0];
        const float2 bb  = *(const float2*)&b1[j0];
        const float bs0 = fmaf(dd0, w2x.x, fmaf(dd1, w2y.x, fmaf(dd2, w2z.x, bb.x)));
        const float bs1 = fmaf(dd0, w2x.y, fmaf(dd1, w2y.y, fmaf(dd2, w2z.y, bb.y)));
        uint4 v;
        v.x = bits(pk(w1x.x, w1x.y));
        v.y = bits(pk(w1y.x, w1y.y));
        v.z = bits(pk(w1z.x, w1z.y));
        v.w = bits(pk(bs0, bs1));
        ldsA[r][jp] = v;
    }
    if (tid < 32) {
        const int j0 = tid * 2;
        const float2 ws = *(const float2*)&w_sigma[j0];
        const float c00 = W_color[j0 * 3 + 0], c01 = W_color[j0 * 3 + 1], c02 = W_color[j0 * 3 + 2];
        const float c10 = W_color[j0 * 3 + 3], c11 = W_color[j0 * 3 + 4], c12 = W_color[j0 * 3 + 5];
        uint4 v;
        v.x = bits(pk(ws.x, ws.y));
        v.y = bits(pk(c00, c10));
        v.z = bits(pk(c01, c11));
        v.w = bits(pk(c02, c12));
        ldsB[tid] = v;
    }
    __syncthreads();

    const int r   = tid >> 4;        // ray within block (0..15)
    const int l   = tid & 15;        // lane within ray (0..15)
    int ray = blockIdx.x * RAYS_PER_BLOCK + r;
    const bool valid = (ray < R);
    if (!valid) ray = R - 1;

    const float o0 = rays_o[ray * 3 + 0];
    const float o1 = rays_o[ray * 3 + 1];
    const float o2 = rays_o[ray * 3 + 2];
    const float d0 = rays_d[ray * 3 + 0];
    const float d1 = rays_d[ray * 3 + 1];
    const float d2 = rays_d[ray * 3 + 2];

    // ---- near/far: cube AABB [-1,1]^3 ----
    const float inv0 = 1.0f / (d0 + 1e-15f);
    const float inv1 = 1.0f / (d1 + 1e-15f);
    const float inv2 = 1.0f / (d2 + 1e-15f);
    const float t0a = (-1.0f - o0) * inv0, t0b = (1.0f - o0) * inv0;
    const float t1a = (-1.0f - o1) * inv1, t1b = (1.0f - o1) * inv1;
    const float t2a = (-1.0f - o2) * inv2, t2b = (1.0f - o2) * inv2;
    float near = fmaxf(fmaxf(fminf(t0a, t0b), fminf(t1a, t1b)), fminf(t2a, t2b));
    float far  = fminf(fminf(fmaxf(t0a, t0b), fmaxf(t1a, t1b)), fmaxf(t2a, t2b));
    if (far < near) { near = 1e9f; far = 1e9f; }
    near = fmaxf(near, 0.05f);
    const float span = far - near;
    const float sample_dist = span * (1.0f / (NSTEPS - 1));

    // ---- sample points, duplicated into f16 pairs ----
    hf2 X0[SPT], X1[SPT], X2[SPT];
#pragma unroll
    for (int k = 0; k < SPT; k++) {
        const int s = l * SPT + k;
        const float t = (float)s * (1.0f / (NSTEPS - 1));
        const float z = fmaf(span, t, near);
        const float x0 = fminf(fmaxf(fmaf(d0, z, o0), -1.0f), 1.0f);
        const float x1 = fminf(fmaxf(fmaf(d1, z, o1), -1.0f), 1.0f);
        const float x2 = fminf(fmaxf(fmaf(d2, z, o2), -1.0f), 1.0f);
        X0[k] = pk(x0, x0);
        X1[k] = pk(x1, x1);
        X2[k] = pk(x2, x2);
    }

    // ---- MLP over 32 hidden-unit pairs, f32 accumulators via dot2 ----
    float aS[SPT] = {0,0,0,0,0,0,0,0};
    float aR[SPT] = {0,0,0,0,0,0,0,0};
    float aG[SPT] = {0,0,0,0,0,0,0,0};
    float aB[SPT] = {0,0,0,0,0,0,0,0};
    const hf2 zero2 = {(_Float16)0, (_Float16)0};

#pragma unroll 2
    for (int jp = 0; jp < 32; jp++) {
        const uint4 A  = ldsA[r][jp];
        const uint4 Bq = ldsB[jp];
        const hf2 w1x = unbits(A.x);
        const hf2 w1y = unbits(A.y);
        const hf2 w1z = unbits(A.z);
        const hf2 bse = unbits(A.w);
        const hf2 wsg = unbits(Bq.x);
        const hf2 wcr = unbits(Bq.y);
        const hf2 wcg = unbits(Bq.z);
        const hf2 wcb = unbits(Bq.w);
#pragma unroll
        for (int k = 0; k < SPT; k++) {
            hf2 h = __builtin_elementwise_fma(X0[k], w1x,
                    __builtin_elementwise_fma(X1[k], w1y,
                    __builtin_elementwise_fma(X2[k], w1z, bse)));
            h = __builtin_elementwise_max(h, zero2);     // relu -> v_pk_max_f16
            aS[k] = dot2acc(h, wsg, aS[k]);
            aR[k] = dot2acc(h, wcr, aR[k]);
            aG[k] = dot2acc(h, wcg, aG[k]);
            aB[k] = dot2acc(h, wcb, aB[k]);
        }
    }

    // ---- sigma -> alpha, thread-local transmittance ----
    float alpha[SPT], Tloc[SPT];
    float pl = 1.0f;
#pragma unroll
    for (int k = 0; k < SPT; k++) {
        const float x = aS[k];
        const float sig = fmaxf(x, 0.0f) + __logf(1.0f + __expf(-fabsf(x)));
        alpha[k] = 1.0f - __expf(-sample_dist * sig);
        Tloc[k] = pl;
        pl *= (1.0f - alpha[k] + 1e-15f);
    }

    // ---- exclusive scan of products across the 16 lanes of this ray ----
    float inc = pl;
#pragma unroll
    for (int dlt = 1; dlt < THREADS_PER_RAY; dlt <<= 1) {
        const float v = __shfl_up(inc, dlt, THREADS_PER_RAY);
        if (l >= dlt) inc *= v;
    }
    float excl = __shfl_up(inc, 1, THREADS_PER_RAY);
    if (l == 0) excl = 1.0f;

    // ---- weights, color, depth ----
    float w[SPT];
    float wsum = 0.f, dep = 0.f, im0 = 0.f, im1 = 0.f, im2 = 0.f;
#pragma unroll
    for (int k = 0; k < SPT; k++) {
        const int s = l * SPT + k;
        const float t = (float)s * (1.0f / (NSTEPS - 1));
        const float z = fmaf(span, t, near);
        const float T  = excl * Tloc[k];
        const float wt = alpha[k] * T;
        w[k] = wt;
        wsum += wt;
        dep  += wt * z;
        const float cr = 1.0f / (1.0f + __expf(-aR[k]));
        const float cg = 1.0f / (1.0f + __expf(-aG[k]));
        const float cb = 1.0f / (1.0f + __expf(-aB[k]));
        im0 += wt * cr;
        im1 += wt * cg;
        im2 += wt * cb;
    }

    if (valid) {
        float* wp = &out_weights[(size_t)ray * NSTEPS + l * SPT];
        *(float4*)(wp + 0) = make_float4(w[0], w[1], w[2], w[3]);
        *(float4*)(wp + 4) = make_float4(w[4], w[5], w[6], w[7]);
    }

    // ---- reduce across the ray's 16 lanes ----
#pragma unroll
    for (int dlt = THREADS_PER_RAY / 2; dlt >= 1; dlt >>= 1) {
        wsum += __shfl_down(wsum, dlt, THREADS_PER_RAY);
        dep  += __shfl_down(dep,  dlt, THREADS_PER_RAY);
        im0  += __shfl_down(im0,  dlt, THREADS_PER_RAY);
        im1  += __shfl_down(im1,  dlt, THREADS_PER_RAY);
        im2  += __shfl_down(im2,  dlt, THREADS_PER_RAY);
    }
    if (l == 0 && valid) {
        out_image[ray * 3 + 0] = im0;
        out_image[ray * 3 + 1] = im1;
        out_image[ray * 3 + 2] = im2;
        out_depth[ray] = dep;
        out_wsum[ray]  = wsum;
    }
}

extern "C" void kernel_launch(void* const* d_in, const int* in_sizes, int n_in,
                              void* d_out, int out_size, void* d_ws, size_t ws_size,
                              hipStream_t stream) {
    const float* rays_o  = (const float*)d_in[0];
    const float* rays_d  = (const float*)d_in[1];
    const float* W1      = (const float*)d_in[2];
    const float* W2      = (const float*)d_in[3];
    const float* b1      = (const float*)d_in[4];
    const float* w_sigma = (const float*)d_in[5];
    const float* W_color = (const float*)d_in[6];

    const int R = in_sizes[0] / 3;  // B*N rays

    float* out         = (float*)d_out;
    float* out_image   = out;                               // [R,3]
    float* out_depth   = out_image + (size_t)R * 3;         // [R]
    float* out_weights = out_depth + R;                     // [R,128]
    float* out_wsum    = out_weights + (size_t)R * NSTEPS;  // [R]

    const int blocks = (R + RAYS_PER_BLOCK - 1) / RAYS_PER_BLOCK;
    nerf_render_kernel<<<blocks, 256, 0, stream>>>(
        rays_o, rays_d, W1, W2, b1, w_sigma, W_color,
        out_image, out_depth, out_weights, out_wsum, R);
}